// Round 10
// baseline (663.061 us; speedup 1.0000x reference)
//
#include <hip/hip_runtime.h>
#include <cstdint>
#include <cstddef>

// ---------------- problem constants ----------------
constexpr int NNODES = 50000;
constexpr int NEDGES = 500000;
constexpr int NRELS  = 8;
constexpr int DIM    = 128;
constexpr int ADIM   = 64;
constexpr int TWOD   = 256;
constexpr int EPB    = 64;
constexpr float SLOPE = 0.01f;

constexpr int XPITCH = TWOD + 8;
constexpr int SPAD = NEDGES + 1024;

typedef __attribute__((ext_vector_type(8))) short short8;
typedef __attribute__((ext_vector_type(4))) float floatx4;

__device__ __forceinline__ unsigned short f2bf(float f) {
    unsigned u = __float_as_uint(f);
    unsigned r = u + 0x7FFFu + ((u >> 16) & 1u);
    return (unsigned short)(r >> 16);
}
__device__ __forceinline__ float bf2f(unsigned short b) {
    return __uint_as_float(((unsigned)b) << 16);
}

// ---------------- init ----------------
__global__ void k_init(uint2* __restrict__ sMeta, int* __restrict__ histD,
                       int* __restrict__ cursorD, int* __restrict__ cnts) {
    int i = blockIdx.x * blockDim.x + threadIdx.x;
    int stride = gridDim.x * blockDim.x;
    for (int idx = i; idx < SPAD; idx += stride) sMeta[idx] = make_uint2(0xFFFFFFFFu, 0u);
    for (int idx = i; idx < NNODES; idx += stride) { histD[idx] = 0; cursorD[idx] = 0; }
    if (i < 16) cnts[i] = 0;
}

// ---------------- prep: relT transpose via LDS tile; Wl/Wa16 linear ----------------
__global__ __launch_bounds__(256) void k_prep(const float* __restrict__ rel,
                                              const float* __restrict__ W_lin,
                                              const float* __restrict__ W_a,
                                              unsigned short* __restrict__ relT,
                                              unsigned short* __restrict__ Wl,
                                              unsigned short* __restrict__ Wa16) {
    __shared__ float ls[64][65];
    int b = blockIdx.x, t = threadIdx.x;
    if (b < 64) {
        int r = b >> 3, tile = b & 7;
        int d0 = (tile >> 1) * 64, o0 = (tile & 1) * 64;
        const float* rp = rel + ((size_t)r * TWOD + d0) * DIM + o0;
#pragma unroll
        for (int u = 0; u < 16; u++) {
            int v = u * 256 + t;
            int j = v & 63, i = v >> 6;
            ls[i][j] = rp[(size_t)i * DIM + j];
        }
        __syncthreads();
        unsigned short* wp = relT + ((size_t)r * DIM + o0) * TWOD + d0;
#pragma unroll
        for (int u = 0; u < 16; u++) {
            int v = u * 256 + t;
            int ii = v & 63, jj = v >> 6;
            wp[(size_t)jj * TWOD + ii] = f2bf(ls[ii][jj]);
        }
    } else {
        int idx = (b - 64) * 256 + t;
        if (idx < DIM * TWOD) {
            Wl[idx] = f2bf(W_lin[idx]);
        } else {
            int j = idx - DIM * TWOD;
            if (j < ADIM * TWOD) Wa16[j] = f2bf(W_a[j]);
        }
    }
}

// ---------------- h -> bf16 ----------------
__global__ void k_h16(const float* __restrict__ h, unsigned short* __restrict__ h16) {
    int i = blockIdx.x * 256 + threadIdx.x;
    if (i < NNODES * DIM / 8) {
        const float4* hp = (const float4*)(h + (size_t)i * 8);
        float4 a = hp[0], b = hp[1];
        union { unsigned short us[8]; short8 s8; } pk;
        pk.us[0] = f2bf(a.x); pk.us[1] = f2bf(a.y); pk.us[2] = f2bf(a.z); pk.us[3] = f2bf(a.w);
        pk.us[4] = f2bf(b.x); pk.us[5] = f2bf(b.y); pk.us[6] = f2bf(b.z); pk.us[7] = f2bf(b.w);
        *(short8*)&h16[(size_t)i * 8] = pk.s8;
    }
}

// ---------------- fused histogram ----------------
__global__ void k_hist2(const int* __restrict__ ety, const int* __restrict__ dst,
                        int* __restrict__ cnt, int* __restrict__ histD) {
    __shared__ int hist[NRELS];
    int t = threadIdx.x;
    if (t < NRELS) hist[t] = 0;
    __syncthreads();
    int e = blockIdx.x * 256 + t;
    if (e < NEDGES) {
        atomicAdd(&hist[ety[e]], 1);
        atomicAdd(&histD[dst[e]], 1);
    }
    __syncthreads();
    if (t < NRELS && hist[t] > 0) atomicAdd(&cnt[t], hist[t]);
}

// ---------------- scan ----------------
__global__ __launch_bounds__(1024) void k_scan(const int* __restrict__ histD,
                                               int* __restrict__ row_ptr,
                                               const int* __restrict__ cnt,
                                               int* __restrict__ offs) {
    __shared__ int ls[1024];
    const int t = threadIdx.x;
    const int CH = (NNODES + 1023) / 1024;
    const int base = t * CH;
    int s = 0;
    for (int j = 0; j < CH; j++) { int i = base + j; if (i < NNODES) s += histD[i]; }
    ls[t] = s;
    __syncthreads();
    for (int off = 1; off < 1024; off <<= 1) {
        int v = (t >= off) ? ls[t - off] : 0;
        __syncthreads();
        ls[t] += v;
        __syncthreads();
    }
    int run = (t == 0) ? 0 : ls[t - 1];
    for (int j = 0; j < CH; j++) {
        int i = base + j;
        if (i < NNODES) { row_ptr[i] = run; run += histD[i]; }
    }
    if (t == 1023) row_ptr[NNODES] = ls[1023];
    if (t == 0) {
        int off = 0;
        for (int r = 0; r < NRELS; r++) {
            offs[r] = off;
            off += ((cnt[r] + EPB - 1) / EPB) * EPB;
        }
    }
}

// ---------------- scatter into dst-CSR order: meta2[p] = (src|dst<<16, ety) ----------------
__global__ void k_dscatter(const int* __restrict__ ety, const int* __restrict__ src,
                           const int* __restrict__ dst, const int* __restrict__ row_ptr,
                           int* __restrict__ cursorD, uint2* __restrict__ meta2) {
    int e = blockIdx.x * 256 + threadIdx.x;
    if (e < NEDGES) {
        int dn = dst[e];
        int pos = row_ptr[dn] + atomicAdd(&cursorD[dn], 1);
        meta2[pos] = make_uint2((unsigned)src[e] | ((unsigned)dn << 16), (unsigned)ety[e]);
    }
}

// ---------------- scatter p-order -> etype buckets: sMeta[s] = (src|dst<<16, p) ----------------
__global__ void k_scatter3(const uint2* __restrict__ meta2, const int* __restrict__ offs,
                           int* __restrict__ cursorE, uint2* __restrict__ sMeta) {
    __shared__ int hist[NRELS];
    __shared__ int basew[NRELS];
    int t = threadIdx.x;
    if (t < NRELS) hist[t] = 0;
    __syncthreads();
    int p = blockIdx.x * 256 + t;
    int r = -1, rank = 0;
    uint2 m2 = make_uint2(0u, 0u);
    if (p < NEDGES) {
        m2 = meta2[p];
        r = (int)m2.y;
        rank = atomicAdd(&hist[r], 1);
    }
    __syncthreads();
    if (t < NRELS && hist[t] > 0) basew[t] = atomicAdd(&cursorE[t], hist[t]);
    __syncthreads();
    if (p < NEDGES) {
        int s = offs[r] + basew[r] + rank;
        sMeta[s] = make_uint2(m2.x, (unsigned)p);
    }
}

// ---------------- gates + messages + scores: single merged MFMA K-loop ----------------
__global__ __launch_bounds__(256) void k_gate_msg(
    const unsigned short* __restrict__ h16, const unsigned short* __restrict__ relT,
    const unsigned short* __restrict__ Wa16,
    const uint2* __restrict__ sMeta, const float* __restrict__ b_a,
    const float* __restrict__ ratt, const int* __restrict__ offs,
    unsigned short* __restrict__ msgbuf, float* __restrict__ scoreP) {
    __shared__ unsigned short Xs[EPB * XPITCH];   // 33792 B
    __shared__ int srcn_s[EPB];
    __shared__ int dstn_s[EPB];
    __shared__ int pos_s[EPB];
    __shared__ int val_s[EPB];
    __shared__ float scoreW[EPB][4];

    const int t = threadIdx.x;
    const int base = blockIdx.x * EPB;

    if (t < EPB) {
        uint2 m2 = sMeta[base + t];
        int valid = (m2.x != 0xFFFFFFFFu);
        val_s[t] = valid;
        srcn_s[t] = valid ? (int)(m2.x & 0xFFFFu) : 0;
        dstn_s[t] = valid ? (int)(m2.x >> 16) : 0;
        pos_s[t] = valid ? (int)m2.y : 0;
    }
    __syncthreads();
    if (!val_s[0]) return;

    int r = 0;
#pragma unroll
    for (int i = 1; i < NRELS; i++) if (base >= offs[i]) r = i;

#pragma unroll
    for (int u = 0; u < 8; u++) {
        int v = u * 256 + t;
        int i = v >> 5;
        int c = v & 31;
        int node = (c < 16) ? dstn_s[i] : srcn_s[i];
        *(short8*)&Xs[i * XPITCH + c * 8] = *(const short8*)&h16[(size_t)node * DIM + (c & 15) * 8];
    }

    const int wave = t >> 6;
    const int lane = t & 63;
    const int q = lane >> 4;
    const int l16 = lane & 15;
    const int o16 = wave * 16 + l16;

    const unsigned short* bp0 = relT + ((size_t)r * DIM + (wave * 2 + 0) * 16 + l16) * TWOD + q * 8;
    const unsigned short* bp1 = relT + ((size_t)r * DIM + (wave * 2 + 1) * 16 + l16) * TWOD + q * 8;
    const unsigned short* wb  = Wa16 + (size_t)o16 * TWOD + q * 8;

    __syncthreads();

    floatx4 acc[4][2];
    floatx4 accS[4];
#pragma unroll
    for (int m = 0; m < 4; m++) {
        acc[m][0] = (floatx4)(0.0f);
        acc[m][1] = (floatx4)(0.0f);
        accS[m] = (floatx4)(0.0f);
    }

#pragma unroll
    for (int ks = 0; ks < 8; ks++) {
        short8 B0 = *(const short8*)(bp0 + ks * 32);
        short8 B1 = *(const short8*)(bp1 + ks * 32);
        short8 BS = *(const short8*)(wb + ks * 32);
        short8 Af[4];
        const unsigned short* xb = &Xs[l16 * XPITCH + ks * 32 + q * 8];
#pragma unroll
        for (int m = 0; m < 4; m++) Af[m] = *(const short8*)(xb + m * 16 * XPITCH);
#pragma unroll
        for (int m = 0; m < 4; m++) {
            acc[m][0] = __builtin_amdgcn_mfma_f32_16x16x32_bf16(Af[m], B0, acc[m][0], 0, 0, 0);
            acc[m][1] = __builtin_amdgcn_mfma_f32_16x16x32_bf16(Af[m], B1, acc[m][1], 0, 0, 0);
            accS[m]   = __builtin_amdgcn_mfma_f32_16x16x32_bf16(Af[m], BS, accS[m], 0, 0, 0);
        }
    }

    __syncthreads();  // all Xs reads done before overwriting dst half

    // score epilogue
    {
        float ba = b_a[o16];
        float ra = ratt[o16];
#pragma unroll
        for (int m = 0; m < 4; m++) {
#pragma unroll
            for (int rg = 0; rg < 4; rg++) {
                float v = accS[m][rg] + ba;
                v = v > 0.0f ? v : SLOPE * v;
                v *= ra;
#pragma unroll
                for (int off = 8; off > 0; off >>= 1) v += __shfl_xor(v, off, 16);
                if (l16 == 0) scoreW[m * 16 + q * 4 + rg][wave] = v;
            }
        }
    }

    // gate epilogue: msg = sigmoid(acc) * src_h -> Xs dst half (bf16)
#pragma unroll
    for (int m = 0; m < 4; m++) {
        int ib = m * 16 + q * 4;
#pragma unroll
        for (int nn = 0; nn < 2; nn++) {
            int o = (wave * 2 + nn) * 16 + l16;
#pragma unroll
            for (int rg = 0; rg < 4; rg++) {
                int i = ib + rg;
                float g = 1.0f / (1.0f + __expf(-acc[m][nn][rg]));
                float sh = bf2f(Xs[i * XPITCH + DIM + o]);
                Xs[i * XPITCH + o] = f2bf(sh * g);
            }
        }
    }
    __syncthreads();

#pragma unroll
    for (int u = 0; u < 4; u++) {
        int v = u * 256 + t;
        int i = v >> 4;
        int c = v & 15;
        if (!val_s[i]) continue;
        short8 val = *(const short8*)&Xs[i * XPITCH + c * 8];
        *(short8*)&msgbuf[(size_t)pos_s[i] * DIM + c * 8] = val;
    }
    if (t < EPB && val_s[t]) {
        scoreP[pos_s[t]] = scoreW[t][0] + scoreW[t][1] + scoreW[t][2] + scoreW[t][3];
    }
}

// ---------------- fused: softmax + weighted segment-sum + output GEMM ----------------
// Per 64-node block: phase A aggregates msg runs (softmax inline) into Xs cols 128..255;
// phase B stages h16 into cols 0..127; then k_out's GEMM.
__global__ __launch_bounds__(256) void k_aggr_out(
    const unsigned short* __restrict__ h16, const unsigned short* __restrict__ msgbuf,
    const float* __restrict__ scoreP, const int* __restrict__ row_ptr,
    const unsigned short* __restrict__ Wl, const float* __restrict__ b_lin,
    float* __restrict__ out) {
    __shared__ unsigned short Xs[EPB * XPITCH];
    const int t = threadIdx.x;
    const int nb = blockIdx.x * 64;
    const int wave = t >> 6;
    const int lane = t & 63;

    // phase A: each wave aggregates 16 nodes (lane covers 2 cols)
    for (int j = 0; j < 16; j++) {
        int i = wave * 16 + j;
        int n = nb + i;
        float a0 = 0.0f, a1 = 0.0f;
        if (n < NNODES) {
            int p0 = row_ptr[n], p1 = row_ptr[n + 1];
            if (p0 < p1) {
                float mx = -3.0e38f;
                for (int p = p0; p < p1; p++) mx = fmaxf(mx, scoreP[p]);
                float sum = 0.0f;
                for (int p = p0; p < p1; p++) sum += __expf(scoreP[p] - mx);
                float inv = 1.0f / sum;
                for (int p = p0; p < p1; p++) {
                    float w = __expf(scoreP[p] - mx) * inv;
                    unsigned v = *(const unsigned*)&msgbuf[(size_t)p * DIM + lane * 2];
                    a0 += w * bf2f((unsigned short)(v & 0xFFFFu));
                    a1 += w * bf2f((unsigned short)(v >> 16));
                }
            }
        }
        unsigned o = (unsigned)f2bf(a0) | ((unsigned)f2bf(a1) << 16);
        *(unsigned*)&Xs[i * XPITCH + DIM + lane * 2] = o;
    }

    // phase B: stage h16 rows into cols 0..127
#pragma unroll
    for (int u = 0; u < 4; u++) {
        int v = u * 256 + t;
        int i = v >> 4;
        int c = v & 15;
        int n = nb + i;
        if (n >= NNODES) n = NNODES - 1;
        *(short8*)&Xs[i * XPITCH + c * 8] = *(const short8*)&h16[(size_t)n * DIM + c * 8];
    }

    const int q = lane >> 4;
    const int l16 = lane & 15;

    short8 Bf[2][8];
#pragma unroll
    for (int nn = 0; nn < 2; nn++) {
        int o = (wave * 2 + nn) * 16 + l16;
        const unsigned short* bp = Wl + (size_t)o * TWOD + q * 8;
#pragma unroll
        for (int ks = 0; ks < 8; ks++) Bf[nn][ks] = *(const short8*)(bp + ks * 32);
    }

    __syncthreads();

    floatx4 acc[4][2];
#pragma unroll
    for (int m = 0; m < 4; m++)
#pragma unroll
        for (int nn = 0; nn < 2; nn++) acc[m][nn] = (floatx4)(0.0f);

#pragma unroll
    for (int ks = 0; ks < 8; ks++) {
        short8 Af[4];
        const unsigned short* xb = &Xs[l16 * XPITCH + ks * 32 + q * 8];
#pragma unroll
        for (int m = 0; m < 4; m++) Af[m] = *(const short8*)(xb + m * 16 * XPITCH);
#pragma unroll
        for (int m = 0; m < 4; m++)
#pragma unroll
            for (int nn = 0; nn < 2; nn++)
                acc[m][nn] = __builtin_amdgcn_mfma_f32_16x16x32_bf16(Af[m], Bf[nn][ks], acc[m][nn], 0, 0, 0);
    }

#pragma unroll
    for (int m = 0; m < 4; m++) {
        int ib = m * 16 + q * 4;
#pragma unroll
        for (int nn = 0; nn < 2; nn++) {
            int o = (wave * 2 + nn) * 16 + l16;
            float bl = b_lin[o];
#pragma unroll
            for (int rg = 0; rg < 4; rg++) {
                int n = nb + ib + rg;
                if (n < NNODES) {
                    float val = acc[m][nn][rg] + bl;
                    val = val > 0.0f ? val : SLOPE * val;
                    out[(size_t)n * DIM + o] = val;
                }
            }
        }
    }
}

// ---------------- launcher ----------------
extern "C" void kernel_launch(void* const* d_in, const int* in_sizes, int n_in,
                              void* d_out, int out_size, void* d_ws, size_t ws_size,
                              hipStream_t stream) {
    const float* h     = (const float*)d_in[0];
    const float* rel   = (const float*)d_in[1];
    const float* ratt  = (const float*)d_in[2];
    const float* W_a   = (const float*)d_in[3];
    const float* b_a   = (const float*)d_in[4];
    const float* W_lin = (const float*)d_in[5];
    const float* b_lin = (const float*)d_in[6];
    const int* src = (const int*)d_in[7];
    const int* dst = (const int*)d_in[8];
    const int* ety = (const int*)d_in[9];
    float* out = (float*)d_out;

    // workspace layout (~156 MB)
    float* scoreP = (float*)d_ws;                                   // E
    unsigned short* h16  = (unsigned short*)(scoreP + NEDGES);      // N*128 bf16
    unsigned short* relT = h16 + (size_t)NNODES * DIM;              // 8*128*256 bf16
    unsigned short* Wl   = relT + (size_t)NRELS * DIM * TWOD;       // 128*256 bf16
    unsigned short* Wa16 = Wl + (size_t)DIM * TWOD;                 // 64*256 bf16
    uint2* meta2 = (uint2*)(Wa16 + (size_t)ADIM * TWOD);            // E uint2
    uint2* sMeta = meta2 + NEDGES;                                  // SPAD uint2
    int* row_ptr = (int*)(sMeta + SPAD);                            // N+1
    int* histD   = row_ptr + (NNODES + 1);                          // N
    int* cursorD = histD + NNODES;                                  // N
    int* cnts    = cursorD + NNODES;                                // 16
    int* offs    = cnts + 16;                                       // 8
    unsigned short* msgbuf = (unsigned short*)(((uintptr_t)(offs + 8) + 255) & ~(uintptr_t)255); // E*128 bf16

    k_init<<<2048, 256, 0, stream>>>(sMeta, histD, cursorD, cnts);
    k_prep<<<64 + (DIM * TWOD + ADIM * TWOD + 255) / 256, 256, 0, stream>>>(
        rel, W_lin, W_a, relT, Wl, Wa16);
    k_h16<<<(NNODES * DIM / 8 + 255) / 256, 256, 0, stream>>>(h, h16);
    k_hist2<<<(NEDGES + 255) / 256, 256, 0, stream>>>(ety, dst, cnts, histD);
    k_scan<<<1, 1024, 0, stream>>>(histD, row_ptr, cnts, offs);
    k_dscatter<<<(NEDGES + 255) / 256, 256, 0, stream>>>(
        ety, src, dst, row_ptr, cursorD, meta2);
    k_scatter3<<<(NEDGES + 255) / 256, 256, 0, stream>>>(meta2, offs, cnts + 8, sMeta);
    k_gate_msg<<<(NEDGES + 8 * EPB + EPB - 1) / EPB, 256, 0, stream>>>(
        h16, relT, Wa16, sMeta, b_a, ratt, offs, msgbuf, scoreP);
    k_aggr_out<<<(NNODES + 63) / 64, 256, 0, stream>>>(
        h16, msgbuf, scoreP, row_ptr, Wl, b_lin, out);
}

// Round 11
// 468.555 us; speedup vs baseline: 1.4151x; 1.4151x over previous
//
#include <hip/hip_runtime.h>
#include <cstdint>
#include <cstddef>

// ---------------- problem constants ----------------
constexpr int NNODES = 50000;
constexpr int NEDGES = 500000;
constexpr int NRELS  = 8;
constexpr int DIM    = 128;
constexpr int ADIM   = 64;
constexpr int TWOD   = 256;
constexpr int EPB    = 64;
constexpr float SLOPE = 0.01f;

constexpr int XPITCH = TWOD + 8;
constexpr int SPAD = NEDGES + 1024;

typedef __attribute__((ext_vector_type(8))) short short8;
typedef __attribute__((ext_vector_type(4))) float floatx4;

__device__ __forceinline__ unsigned short f2bf(float f) {
    unsigned u = __float_as_uint(f);
    unsigned r = u + 0x7FFFu + ((u >> 16) & 1u);
    return (unsigned short)(r >> 16);
}
__device__ __forceinline__ float bf2f(unsigned short b) {
    return __uint_as_float(((unsigned)b) << 16);
}

// ---------------- init ----------------
__global__ void k_init(uint2* __restrict__ sMeta, int* __restrict__ histD,
                       int* __restrict__ cursorD, int* __restrict__ cnts) {
    int i = blockIdx.x * blockDim.x + threadIdx.x;
    int stride = gridDim.x * blockDim.x;
    for (int idx = i; idx < SPAD; idx += stride) sMeta[idx] = make_uint2(0xFFFFFFFFu, 0u);
    for (int idx = i; idx < NNODES; idx += stride) { histD[idx] = 0; cursorD[idx] = 0; }
    if (i < 16) cnts[i] = 0;
}

// ---------------- prep: relT transpose via LDS tile; Wl/Wa16 linear ----------------
__global__ __launch_bounds__(256) void k_prep(const float* __restrict__ rel,
                                              const float* __restrict__ W_lin,
                                              const float* __restrict__ W_a,
                                              unsigned short* __restrict__ relT,
                                              unsigned short* __restrict__ Wl,
                                              unsigned short* __restrict__ Wa16) {
    __shared__ float ls[64][65];
    int b = blockIdx.x, t = threadIdx.x;
    if (b < 64) {
        int r = b >> 3, tile = b & 7;
        int d0 = (tile >> 1) * 64, o0 = (tile & 1) * 64;
        const float* rp = rel + ((size_t)r * TWOD + d0) * DIM + o0;
#pragma unroll
        for (int u = 0; u < 16; u++) {
            int v = u * 256 + t;
            int j = v & 63, i = v >> 6;
            ls[i][j] = rp[(size_t)i * DIM + j];
        }
        __syncthreads();
        unsigned short* wp = relT + ((size_t)r * DIM + o0) * TWOD + d0;
#pragma unroll
        for (int u = 0; u < 16; u++) {
            int v = u * 256 + t;
            int ii = v & 63, jj = v >> 6;
            wp[(size_t)jj * TWOD + ii] = f2bf(ls[ii][jj]);
        }
    } else {
        int idx = (b - 64) * 256 + t;
        if (idx < DIM * TWOD) {
            Wl[idx] = f2bf(W_lin[idx]);
        } else {
            int j = idx - DIM * TWOD;
            if (j < ADIM * TWOD) Wa16[j] = f2bf(W_a[j]);
        }
    }
}

// ---------------- h -> bf16 ----------------
__global__ void k_h16(const float* __restrict__ h, unsigned short* __restrict__ h16) {
    int i = blockIdx.x * 256 + threadIdx.x;
    if (i < NNODES * DIM / 8) {
        const float4* hp = (const float4*)(h + (size_t)i * 8);
        float4 a = hp[0], b = hp[1];
        union { unsigned short us[8]; short8 s8; } pk;
        pk.us[0] = f2bf(a.x); pk.us[1] = f2bf(a.y); pk.us[2] = f2bf(a.z); pk.us[3] = f2bf(a.w);
        pk.us[4] = f2bf(b.x); pk.us[5] = f2bf(b.y); pk.us[6] = f2bf(b.z); pk.us[7] = f2bf(b.w);
        *(short8*)&h16[(size_t)i * 8] = pk.s8;
    }
}

// ---------------- fused histogram ----------------
__global__ void k_hist2(const int* __restrict__ ety, const int* __restrict__ dst,
                        int* __restrict__ cnt, int* __restrict__ histD) {
    __shared__ int hist[NRELS];
    int t = threadIdx.x;
    if (t < NRELS) hist[t] = 0;
    __syncthreads();
    int e = blockIdx.x * 256 + t;
    if (e < NEDGES) {
        atomicAdd(&hist[ety[e]], 1);
        atomicAdd(&histD[dst[e]], 1);
    }
    __syncthreads();
    if (t < NRELS && hist[t] > 0) atomicAdd(&cnt[t], hist[t]);
}

// ---------------- scan ----------------
__global__ __launch_bounds__(1024) void k_scan(const int* __restrict__ histD,
                                               int* __restrict__ row_ptr,
                                               const int* __restrict__ cnt,
                                               int* __restrict__ offs) {
    __shared__ int ls[1024];
    const int t = threadIdx.x;
    const int CH = (NNODES + 1023) / 1024;
    const int base = t * CH;
    int s = 0;
    for (int j = 0; j < CH; j++) { int i = base + j; if (i < NNODES) s += histD[i]; }
    ls[t] = s;
    __syncthreads();
    for (int off = 1; off < 1024; off <<= 1) {
        int v = (t >= off) ? ls[t - off] : 0;
        __syncthreads();
        ls[t] += v;
        __syncthreads();
    }
    int run = (t == 0) ? 0 : ls[t - 1];
    for (int j = 0; j < CH; j++) {
        int i = base + j;
        if (i < NNODES) { row_ptr[i] = run; run += histD[i]; }
    }
    if (t == 1023) row_ptr[NNODES] = ls[1023];
    if (t == 0) {
        int off = 0;
        for (int r = 0; r < NRELS; r++) {
            offs[r] = off;
            off += ((cnt[r] + EPB - 1) / EPB) * EPB;
        }
    }
}

// ---------------- single-pass scatter: dst-CSR position + etype bucket slot ----------------
// sMeta[s] = (src | dst<<16, pos); pos = slot in dst-CSR (msgbuf/scoreP index).
__global__ void k_escatter(const int* __restrict__ ety, const int* __restrict__ src,
                           const int* __restrict__ dst, const int* __restrict__ row_ptr,
                           const int* __restrict__ offs,
                           int* __restrict__ cursorD, int* __restrict__ cursorE,
                           uint2* __restrict__ sMeta) {
    __shared__ int hist[NRELS];
    __shared__ int basew[NRELS];
    int t = threadIdx.x;
    if (t < NRELS) hist[t] = 0;
    __syncthreads();
    int e = blockIdx.x * 256 + t;
    int r = -1, rank = 0, sn = 0, dn = 0;
    if (e < NEDGES) {
        r = ety[e]; sn = src[e]; dn = dst[e];
        rank = atomicAdd(&hist[r], 1);
    }
    __syncthreads();
    if (t < NRELS && hist[t] > 0) basew[t] = atomicAdd(&cursorE[t], hist[t]);
    __syncthreads();
    if (e < NEDGES) {
        int s = offs[r] + basew[r] + rank;
        int pos = row_ptr[dn] + atomicAdd(&cursorD[dn], 1);
        sMeta[s] = make_uint2((unsigned)sn | ((unsigned)dn << 16), (unsigned)pos);
    }
}

// ---------------- gates + messages + scores: single merged MFMA K-loop ----------------
__global__ __launch_bounds__(256) void k_gate_msg(
    const unsigned short* __restrict__ h16, const unsigned short* __restrict__ relT,
    const unsigned short* __restrict__ Wa16,
    const uint2* __restrict__ sMeta, const float* __restrict__ b_a,
    const float* __restrict__ ratt, const int* __restrict__ offs,
    unsigned short* __restrict__ msgbuf, float* __restrict__ scoreP) {
    __shared__ unsigned short Xs[EPB * XPITCH];   // 33792 B
    __shared__ int srcn_s[EPB];
    __shared__ int dstn_s[EPB];
    __shared__ int pos_s[EPB];
    __shared__ int val_s[EPB];
    __shared__ float scoreW[EPB][4];

    const int t = threadIdx.x;
    const int base = blockIdx.x * EPB;

    if (t < EPB) {
        uint2 m2 = sMeta[base + t];
        int valid = (m2.x != 0xFFFFFFFFu);
        val_s[t] = valid;
        srcn_s[t] = valid ? (int)(m2.x & 0xFFFFu) : 0;
        dstn_s[t] = valid ? (int)(m2.x >> 16) : 0;
        pos_s[t] = valid ? (int)m2.y : 0;
    }
    __syncthreads();
    if (!val_s[0]) return;

    int r = 0;
#pragma unroll
    for (int i = 1; i < NRELS; i++) if (base >= offs[i]) r = i;

#pragma unroll
    for (int u = 0; u < 8; u++) {
        int v = u * 256 + t;
        int i = v >> 5;
        int c = v & 31;
        int node = (c < 16) ? dstn_s[i] : srcn_s[i];
        *(short8*)&Xs[i * XPITCH + c * 8] = *(const short8*)&h16[(size_t)node * DIM + (c & 15) * 8];
    }

    const int wave = t >> 6;
    const int lane = t & 63;
    const int q = lane >> 4;
    const int l16 = lane & 15;
    const int o16 = wave * 16 + l16;

    const unsigned short* bp0 = relT + ((size_t)r * DIM + (wave * 2 + 0) * 16 + l16) * TWOD + q * 8;
    const unsigned short* bp1 = relT + ((size_t)r * DIM + (wave * 2 + 1) * 16 + l16) * TWOD + q * 8;
    const unsigned short* wb  = Wa16 + (size_t)o16 * TWOD + q * 8;

    __syncthreads();

    floatx4 acc[4][2];
    floatx4 accS[4];
#pragma unroll
    for (int m = 0; m < 4; m++) {
        acc[m][0] = (floatx4)(0.0f);
        acc[m][1] = (floatx4)(0.0f);
        accS[m] = (floatx4)(0.0f);
    }

#pragma unroll
    for (int ks = 0; ks < 8; ks++) {
        short8 B0 = *(const short8*)(bp0 + ks * 32);
        short8 B1 = *(const short8*)(bp1 + ks * 32);
        short8 BS = *(const short8*)(wb + ks * 32);
        short8 Af[4];
        const unsigned short* xb = &Xs[l16 * XPITCH + ks * 32 + q * 8];
#pragma unroll
        for (int m = 0; m < 4; m++) Af[m] = *(const short8*)(xb + m * 16 * XPITCH);
#pragma unroll
        for (int m = 0; m < 4; m++) {
            acc[m][0] = __builtin_amdgcn_mfma_f32_16x16x32_bf16(Af[m], B0, acc[m][0], 0, 0, 0);
            acc[m][1] = __builtin_amdgcn_mfma_f32_16x16x32_bf16(Af[m], B1, acc[m][1], 0, 0, 0);
            accS[m]   = __builtin_amdgcn_mfma_f32_16x16x32_bf16(Af[m], BS, accS[m], 0, 0, 0);
        }
    }

    __syncthreads();  // all Xs reads done before overwriting dst half

    // score epilogue
    {
        float ba = b_a[o16];
        float ra = ratt[o16];
#pragma unroll
        for (int m = 0; m < 4; m++) {
#pragma unroll
            for (int rg = 0; rg < 4; rg++) {
                float v = accS[m][rg] + ba;
                v = v > 0.0f ? v : SLOPE * v;
                v *= ra;
#pragma unroll
                for (int off = 8; off > 0; off >>= 1) v += __shfl_xor(v, off, 16);
                if (l16 == 0) scoreW[m * 16 + q * 4 + rg][wave] = v;
            }
        }
    }

    // gate epilogue: msg = sigmoid(acc) * src_h -> Xs dst half (bf16)
#pragma unroll
    for (int m = 0; m < 4; m++) {
        int ib = m * 16 + q * 4;
#pragma unroll
        for (int nn = 0; nn < 2; nn++) {
            int o = (wave * 2 + nn) * 16 + l16;
#pragma unroll
            for (int rg = 0; rg < 4; rg++) {
                int i = ib + rg;
                float g = 1.0f / (1.0f + __expf(-acc[m][nn][rg]));
                float sh = bf2f(Xs[i * XPITCH + DIM + o]);
                Xs[i * XPITCH + o] = f2bf(sh * g);
            }
        }
    }
    __syncthreads();

#pragma unroll
    for (int u = 0; u < 4; u++) {
        int v = u * 256 + t;
        int i = v >> 4;
        int c = v & 15;
        if (!val_s[i]) continue;
        short8 val = *(const short8*)&Xs[i * XPITCH + c * 8];
        *(short8*)&msgbuf[(size_t)pos_s[i] * DIM + c * 8] = val;
    }
    if (t < EPB && val_s[t]) {
        scoreP[pos_s[t]] = scoreW[t][0] + scoreW[t][1] + scoreW[t][2] + scoreW[t][3];
    }
}

// ---------------- fused softmax + weighted segment-sum -> hN bf16 ----------------
// One wave per node: lane-parallel max/sum reductions, then col-parallel weighted stream.
__global__ __launch_bounds__(256) void k_aggr(const unsigned short* __restrict__ msgbuf,
                                              const float* __restrict__ scoreP,
                                              const int* __restrict__ row_ptr,
                                              unsigned short* __restrict__ hN16) {
    int n = blockIdx.x * 4 + (threadIdx.x >> 6);
    int lane = threadIdx.x & 63;
    if (n >= NNODES) return;
    int p0 = row_ptr[n], p1 = row_ptr[n + 1];
    float a0 = 0.0f, a1 = 0.0f;
    if (p0 < p1) {
        float mx = -3.0e38f;
        for (int p = p0 + lane; p < p1; p += 64) mx = fmaxf(mx, scoreP[p]);
#pragma unroll
        for (int off = 32; off > 0; off >>= 1) mx = fmaxf(mx, __shfl_xor(mx, off));
        float sum = 0.0f;
        for (int p = p0 + lane; p < p1; p += 64) sum += __expf(scoreP[p] - mx);
#pragma unroll
        for (int off = 32; off > 0; off >>= 1) sum += __shfl_xor(sum, off);
        float inv = 1.0f / sum;
        for (int p = p0; p < p1; p++) {
            float w = __expf(scoreP[p] - mx) * inv;   // broadcast load + cheap exp
            unsigned v = *(const unsigned*)&msgbuf[(size_t)p * DIM + lane * 2];
            a0 += w * bf2f((unsigned short)(v & 0xFFFFu));
            a1 += w * bf2f((unsigned short)(v >> 16));
        }
    }
    unsigned o = (unsigned)f2bf(a0) | ((unsigned)f2bf(a1) << 16);
    *(unsigned*)&hN16[(size_t)n * DIM + lane * 2] = o;
}

// ---------------- out = leaky(W_lin @ [h ; h_N] + b) via MFMA ----------------
__global__ __launch_bounds__(256) void k_out(const unsigned short* __restrict__ h16,
                                             const unsigned short* __restrict__ hN16,
                                             const unsigned short* __restrict__ Wl,
                                             const float* __restrict__ b_lin,
                                             float* __restrict__ out) {
    __shared__ unsigned short Xs[EPB * XPITCH];
    const int t = threadIdx.x;
    const int nb = blockIdx.x * 64;

#pragma unroll
    for (int u = 0; u < 8; u++) {
        int v = u * 256 + t;
        int i = v >> 5;
        int c = v & 31;
        int n = nb + i;
        if (n >= NNODES) n = NNODES - 1;
        const unsigned short* srcp = (c < 16) ? h16 : hN16;
        *(short8*)&Xs[i * XPITCH + c * 8] = *(const short8*)&srcp[(size_t)n * DIM + (c & 15) * 8];
    }

    const int wave = t >> 6;
    const int lane = t & 63;
    const int q = lane >> 4;
    const int l16 = lane & 15;

    short8 Bf[2][8];
#pragma unroll
    for (int nn = 0; nn < 2; nn++) {
        int o = (wave * 2 + nn) * 16 + l16;
        const unsigned short* bp = Wl + (size_t)o * TWOD + q * 8;
#pragma unroll
        for (int ks = 0; ks < 8; ks++) Bf[nn][ks] = *(const short8*)(bp + ks * 32);
    }

    __syncthreads();

    floatx4 acc[4][2];
#pragma unroll
    for (int m = 0; m < 4; m++)
#pragma unroll
        for (int nn = 0; nn < 2; nn++) acc[m][nn] = (floatx4)(0.0f);

#pragma unroll
    for (int ks = 0; ks < 8; ks++) {
        short8 Af[4];
        const unsigned short* xb = &Xs[l16 * XPITCH + ks * 32 + q * 8];
#pragma unroll
        for (int m = 0; m < 4; m++) Af[m] = *(const short8*)(xb + m * 16 * XPITCH);
#pragma unroll
        for (int m = 0; m < 4; m++)
#pragma unroll
            for (int nn = 0; nn < 2; nn++)
                acc[m][nn] = __builtin_amdgcn_mfma_f32_16x16x32_bf16(Af[m], Bf[nn][ks], acc[m][nn], 0, 0, 0);
    }

#pragma unroll
    for (int m = 0; m < 4; m++) {
        int ib = m * 16 + q * 4;
#pragma unroll
        for (int nn = 0; nn < 2; nn++) {
            int o = (wave * 2 + nn) * 16 + l16;
            float bl = b_lin[o];
#pragma unroll
            for (int rg = 0; rg < 4; rg++) {
                int n = nb + ib + rg;
                if (n < NNODES) {
                    float val = acc[m][nn][rg] + bl;
                    val = val > 0.0f ? val : SLOPE * val;
                    out[(size_t)n * DIM + o] = val;
                }
            }
        }
    }
}

// ---------------- launcher ----------------
extern "C" void kernel_launch(void* const* d_in, const int* in_sizes, int n_in,
                              void* d_out, int out_size, void* d_ws, size_t ws_size,
                              hipStream_t stream) {
    const float* h     = (const float*)d_in[0];
    const float* rel   = (const float*)d_in[1];
    const float* ratt  = (const float*)d_in[2];
    const float* W_a   = (const float*)d_in[3];
    const float* b_a   = (const float*)d_in[4];
    const float* W_lin = (const float*)d_in[5];
    const float* b_lin = (const float*)d_in[6];
    const int* src = (const int*)d_in[7];
    const int* dst = (const int*)d_in[8];
    const int* ety = (const int*)d_in[9];
    float* out = (float*)d_out;

    // workspace layout (~161 MB)
    float* scoreP = (float*)d_ws;                                   // E
    unsigned short* h16  = (unsigned short*)(scoreP + NEDGES);      // N*128 bf16
    unsigned short* hN16 = h16 + (size_t)NNODES * DIM;              // N*128 bf16
    unsigned short* relT = hN16 + (size_t)NNODES * DIM;             // 8*128*256 bf16
    unsigned short* Wl   = relT + (size_t)NRELS * DIM * TWOD;       // 128*256 bf16
    unsigned short* Wa16 = Wl + (size_t)DIM * TWOD;                 // 64*256 bf16
    uint2* sMeta = (uint2*)(Wa16 + (size_t)ADIM * TWOD);            // SPAD uint2
    int* row_ptr = (int*)(sMeta + SPAD);                            // N+1
    int* histD   = row_ptr + (NNODES + 1);                          // N
    int* cursorD = histD + NNODES;                                  // N
    int* cnts    = cursorD + NNODES;                                // 16
    int* offs    = cnts + 16;                                       // 8
    unsigned short* msgbuf = (unsigned short*)(((uintptr_t)(offs + 8) + 255) & ~(uintptr_t)255); // E*128 bf16

    k_init<<<2048, 256, 0, stream>>>(sMeta, histD, cursorD, cnts);
    k_prep<<<64 + (DIM * TWOD + ADIM * TWOD + 255) / 256, 256, 0, stream>>>(
        rel, W_lin, W_a, relT, Wl, Wa16);
    k_h16<<<(NNODES * DIM / 8 + 255) / 256, 256, 0, stream>>>(h, h16);
    k_hist2<<<(NEDGES + 255) / 256, 256, 0, stream>>>(ety, dst, cnts, histD);
    k_scan<<<1, 1024, 0, stream>>>(histD, row_ptr, cnts, offs);
    k_escatter<<<(NEDGES + 255) / 256, 256, 0, stream>>>(
        ety, src, dst, row_ptr, offs, cursorD, cnts + 8, sMeta);
    k_gate_msg<<<(NEDGES + 8 * EPB + EPB - 1) / EPB, 256, 0, stream>>>(
        h16, relT, Wa16, sMeta, b_a, ratt, offs, msgbuf, scoreP);
    k_aggr<<<(NNODES + 3) / 4, 256, 0, stream>>>(msgbuf, scoreP, row_ptr, hN16);
    k_out<<<(NNODES + 63) / 64, 256, 0, stream>>>(h16, hN16, Wl, b_lin, out);
}